// Round 1
// baseline (2469.776 us; speedup 1.0000x reference)
//
#include <hip/hip_runtime.h>
#include <math.h>

constexpr int EMBED = 1024;
constexpr int HEADS = 16;
constexpr int HDIM  = 64;     // 1024/16
constexpr int BATCH = 2;
constexpr int SEQ   = 2048;
constexpr int MTOT  = BATCH * SEQ;   // 4096

// ---------------------------------------------------------------------------
// GEMM: C[m,f] = sum_e X[m,e] * W[f,e]   (both row-major, K contiguous)
// 128x128 tile, BK=16, 256 threads, 8x8 micro-tile per thread.
// qkv variant scatters into Q/K/V [b,h,n,d]; proj variant adds bias+relu.
// ---------------------------------------------------------------------------
__global__ __launch_bounds__(256)
void qkv_gemm(const float* __restrict__ X, const float* __restrict__ W,
              float* __restrict__ Q, float* __restrict__ Kp, float* __restrict__ V)
{
    constexpr int BM = 128, BN = 128, BK = 16;
    __shared__ float As[BK][BM + 4];
    __shared__ float Bs[BK][BN + 4];
    const int nbm = MTOT / BM;            // 32
    const int bm  = blockIdx.x % nbm;
    const int bn  = blockIdx.x / nbm;
    const int tid = threadIdx.x;
    const int tm  = (tid / 16) * 8;
    const int tn  = (tid % 16) * 8;

    float acc[8][8] = {};
    const float* Xp = X + (size_t)bm * BM * EMBED;
    const float* Wp = W + (size_t)bn * BN * EMBED;

    for (int k0 = 0; k0 < EMBED; k0 += BK) {
        #pragma unroll
        for (int t = 0; t < 2; ++t) {
            int f4  = tid + t * 256;          // 0..511 float4 slots (128 rows x 4)
            int row = f4 >> 2;
            int col = (f4 & 3) * 4;
            float4 a = *reinterpret_cast<const float4*>(&Xp[(size_t)row * EMBED + k0 + col]);
            As[col + 0][row] = a.x; As[col + 1][row] = a.y;
            As[col + 2][row] = a.z; As[col + 3][row] = a.w;
            float4 b = *reinterpret_cast<const float4*>(&Wp[(size_t)row * EMBED + k0 + col]);
            Bs[col + 0][row] = b.x; Bs[col + 1][row] = b.y;
            Bs[col + 2][row] = b.z; Bs[col + 3][row] = b.w;
        }
        __syncthreads();
        #pragma unroll
        for (int kk = 0; kk < BK; ++kk) {
            float a[8], b[8];
            *(float4*)&a[0] = *(const float4*)&As[kk][tm];
            *(float4*)&a[4] = *(const float4*)&As[kk][tm + 4];
            *(float4*)&b[0] = *(const float4*)&Bs[kk][tn];
            *(float4*)&b[4] = *(const float4*)&Bs[kk][tn + 4];
            #pragma unroll
            for (int i = 0; i < 8; ++i)
                #pragma unroll
                for (int j = 0; j < 8; ++j)
                    acc[i][j] = fmaf(a[i], b[j], acc[i][j]);
        }
        __syncthreads();
    }

    // scatter: f -> (h, d, which); which: 0=q 1=k 2=v; dest layout [b,h,n,d]
    #pragma unroll
    for (int i = 0; i < 8; ++i) {
        int m  = bm * BM + tm + i;
        int b_ = m / SEQ, n_ = m % SEQ;
        #pragma unroll
        for (int j = 0; j < 8; ++j) {
            int f   = bn * BN + tn + j;
            int h   = f / (HDIM * 3);
            int rem = f % (HDIM * 3);
            int d   = rem / 3;
            int w   = rem % 3;
            size_t idx = (((size_t)(b_ * HEADS + h) * SEQ) + n_) * HDIM + d;
            float v = acc[i][j];
            if (w == 0)      Q[idx]  = v;
            else if (w == 1) Kp[idx] = v;
            else             V[idx]  = v;
        }
    }
}

__global__ __launch_bounds__(256)
void proj_gemm(const float* __restrict__ A, const float* __restrict__ W,
               const float* __restrict__ bias, float* __restrict__ Out)
{
    constexpr int BM = 128, BN = 128, BK = 16;
    __shared__ float As[BK][BM + 4];
    __shared__ float Bs[BK][BN + 4];
    const int nbm = MTOT / BM;
    const int bm  = blockIdx.x % nbm;
    const int bn  = blockIdx.x / nbm;
    const int tid = threadIdx.x;
    const int tm  = (tid / 16) * 8;
    const int tn  = (tid % 16) * 8;

    float acc[8][8] = {};
    const float* Ap = A + (size_t)bm * BM * EMBED;
    const float* Wp = W + (size_t)bn * BN * EMBED;

    for (int k0 = 0; k0 < EMBED; k0 += BK) {
        #pragma unroll
        for (int t = 0; t < 2; ++t) {
            int f4  = tid + t * 256;
            int row = f4 >> 2;
            int col = (f4 & 3) * 4;
            float4 a = *reinterpret_cast<const float4*>(&Ap[(size_t)row * EMBED + k0 + col]);
            As[col + 0][row] = a.x; As[col + 1][row] = a.y;
            As[col + 2][row] = a.z; As[col + 3][row] = a.w;
            float4 b = *reinterpret_cast<const float4*>(&Wp[(size_t)row * EMBED + k0 + col]);
            Bs[col + 0][row] = b.x; Bs[col + 1][row] = b.y;
            Bs[col + 2][row] = b.z; Bs[col + 3][row] = b.w;
        }
        __syncthreads();
        #pragma unroll
        for (int kk = 0; kk < BK; ++kk) {
            float a[8], b[8];
            *(float4*)&a[0] = *(const float4*)&As[kk][tm];
            *(float4*)&a[4] = *(const float4*)&As[kk][tm + 4];
            *(float4*)&b[0] = *(const float4*)&Bs[kk][tn];
            *(float4*)&b[4] = *(const float4*)&Bs[kk][tn + 4];
            #pragma unroll
            for (int i = 0; i < 8; ++i)
                #pragma unroll
                for (int j = 0; j < 8; ++j)
                    acc[i][j] = fmaf(a[i], b[j], acc[i][j]);
        }
        __syncthreads();
    }

    #pragma unroll
    for (int i = 0; i < 8; ++i) {
        int m = bm * BM + tm + i;
        #pragma unroll
        for (int j = 0; j < 8; j += 4) {
            int f = bn * BN + tn + j;
            float4 o;
            o.x = fmaxf(acc[i][j + 0] + bias[f + 0], 0.f);
            o.y = fmaxf(acc[i][j + 1] + bias[f + 1], 0.f);
            o.z = fmaxf(acc[i][j + 2] + bias[f + 2], 0.f);
            o.w = fmaxf(acc[i][j + 3] + bias[f + 3], 0.f);
            *(float4*)&Out[(size_t)m * EMBED + f] = o;
        }
    }
}

// ---------------------------------------------------------------------------
// Attention: one q-row per thread, online softmax, K/V staged in LDS.
// softmax(energy) / sqrt(EMBED)  -> fold /32 into final normalization.
// Output CTX in [b, n, h*64+d] layout (row-major for proj GEMM).
// ---------------------------------------------------------------------------
__global__ __launch_bounds__(256)
void attn(const float* __restrict__ Q, const float* __restrict__ Kp,
          const float* __restrict__ V, float* __restrict__ CTX)
{
    constexpr int KB = 32;
    __shared__ float kt[KB][HDIM];
    __shared__ float vt[KB][HDIM];
    const int bh   = blockIdx.y;          // 0..31
    const int b_   = bh / HEADS;
    const int h    = bh % HEADS;
    const int qrow = blockIdx.x * 256 + threadIdx.x;
    const int tid  = threadIdx.x;

    const float* qptr = Q + ((size_t)bh * SEQ + qrow) * HDIM;
    float qv[HDIM];
    #pragma unroll
    for (int i = 0; i < HDIM; i += 4) {
        float4 t = *(const float4*)&qptr[i];
        qv[i] = t.x; qv[i + 1] = t.y; qv[i + 2] = t.z; qv[i + 3] = t.w;
    }

    float mrun = -1e30f, lrun = 0.f;
    float acc[HDIM] = {};
    const float* kbase = Kp + (size_t)bh * SEQ * HDIM;
    const float* vbase = V  + (size_t)bh * SEQ * HDIM;

    for (int k0 = 0; k0 < SEQ; k0 += KB) {
        __syncthreads();
        #pragma unroll
        for (int t = 0; t < 2; ++t) {
            int f4  = tid + t * 256;          // 0..511 (32 rows x 16 float4)
            int row = f4 >> 4;
            int col = (f4 & 15) * 4;
            *(float4*)&kt[row][col] = *(const float4*)&kbase[(size_t)(k0 + row) * HDIM + col];
            *(float4*)&vt[row][col] = *(const float4*)&vbase[(size_t)(k0 + row) * HDIM + col];
        }
        __syncthreads();

        float s[KB];
        #pragma unroll
        for (int kk = 0; kk < KB; ++kk) {
            float sum = 0.f;
            #pragma unroll
            for (int d = 0; d < HDIM; ++d)
                sum = fmaf(qv[d], kt[kk][d], sum);
            s[kk] = sum;
        }
        float tmax = s[0];
        #pragma unroll
        for (int kk = 1; kk < KB; ++kk) tmax = fmaxf(tmax, s[kk]);
        float newm = fmaxf(mrun, tmax);
        float corr = __expf(mrun - newm);
        lrun *= corr;
        #pragma unroll
        for (int d = 0; d < HDIM; ++d) acc[d] *= corr;
        #pragma unroll
        for (int kk = 0; kk < KB; ++kk) {
            float p = __expf(s[kk] - newm);
            lrun += p;
            #pragma unroll
            for (int d = 0; d < HDIM; ++d)
                acc[d] = fmaf(p, vt[kk][d], acc[d]);
        }
        mrun = newm;
    }

    float scale = 1.f / (lrun * 32.f);   // sqrt(1024) = 32
    float* dst = CTX + ((size_t)b_ * SEQ + qrow) * EMBED + h * HDIM;
    #pragma unroll
    for (int d = 0; d < HDIM; d += 4) {
        float4 t = make_float4(acc[d] * scale, acc[d + 1] * scale,
                               acc[d + 2] * scale, acc[d + 3] * scale);
        *(float4*)&dst[d] = t;
    }
}

extern "C" void kernel_launch(void* const* d_in, const int* in_sizes, int n_in,
                              void* d_out, int out_size, void* d_ws, size_t ws_size,
                              hipStream_t stream)
{
    const float* x      = (const float*)d_in[0];
    const float* w_qkv  = (const float*)d_in[1];
    const float* w_proj = (const float*)d_in[2];
    const float* b_proj = (const float*)d_in[3];
    float* out = (float*)d_out;
    float* ws  = (float*)d_ws;

    size_t seg = (size_t)BATCH * HEADS * SEQ * HDIM;   // 4 Mi floats = 16 MiB
    float* Q   = ws;
    float* K   = ws + seg;
    float* V   = ws + 2 * seg;
    float* CTX = ws + 3 * seg;

    qkv_gemm<<<dim3((MTOT / 128) * (3 * EMBED / 128)), 256, 0, stream>>>(x, w_qkv, Q, K, V);
    attn<<<dim3(SEQ / 256, BATCH * HEADS), 256, 0, stream>>>(Q, K, V, CTX);
    proj_gemm<<<dim3((MTOT / 128) * (EMBED / 128)), 256, 0, stream>>>(CTX, w_proj, b_proj, out);
}

// Round 2
// 610.273 us; speedup vs baseline: 4.0470x; 4.0470x over previous
//
#include <hip/hip_runtime.h>
#include <math.h>

constexpr int EMBED = 1024;
constexpr int HEADS = 16;
constexpr int HDIM  = 64;
constexpr int BATCH = 2;
constexpr int SEQ   = 2048;
constexpr int MTOT  = BATCH * SEQ;   // 4096

typedef unsigned short u16;
using bf16x8 = __attribute__((ext_vector_type(8))) short;
using f32x16 = __attribute__((ext_vector_type(16))) float;

__device__ __forceinline__ u16 f2bf(float f) {
    unsigned u = __builtin_bit_cast(unsigned, f);
    return (u16)((u + 0x7fffu + ((u >> 16) & 1u)) >> 16);
}
__device__ __forceinline__ float bf2f(u16 h) {
    unsigned u = ((unsigned)h) << 16;
    return __builtin_bit_cast(float, u);
}

// ---------------------------------------------------------------------------
// QKV GEMM (fp32 vector): C[m,f] = sum_e X[m,e] * W[f,e]
// Epilogue splits Q/K into bf16 hi/lo ([bh][n][d]) and writes V transposed
// as bf16 ([bh][d][n]).
// ---------------------------------------------------------------------------
__global__ __launch_bounds__(256)
void qkv_gemm(const float* __restrict__ X, const float* __restrict__ W,
              u16* __restrict__ Qhi, u16* __restrict__ Qlo,
              u16* __restrict__ Khi, u16* __restrict__ Klo,
              u16* __restrict__ Vt)
{
    constexpr int BM = 128, BN = 128, BK = 16;
    __shared__ float As[BK][BM + 4];
    __shared__ float Bs[BK][BN + 4];
    const int nbm = MTOT / BM;            // 32
    const int bm  = blockIdx.x % nbm;
    const int bn  = blockIdx.x / nbm;
    const int tid = threadIdx.x;
    const int tm  = (tid / 16) * 8;
    const int tn  = (tid % 16) * 8;

    float acc[8][8] = {};
    const float* Xp = X + (size_t)bm * BM * EMBED;
    const float* Wp = W + (size_t)bn * BN * EMBED;

    for (int k0 = 0; k0 < EMBED; k0 += BK) {
        #pragma unroll
        for (int t = 0; t < 2; ++t) {
            int f4  = tid + t * 256;
            int row = f4 >> 2;
            int col = (f4 & 3) * 4;
            float4 a = *reinterpret_cast<const float4*>(&Xp[(size_t)row * EMBED + k0 + col]);
            As[col + 0][row] = a.x; As[col + 1][row] = a.y;
            As[col + 2][row] = a.z; As[col + 3][row] = a.w;
            float4 b = *reinterpret_cast<const float4*>(&Wp[(size_t)row * EMBED + k0 + col]);
            Bs[col + 0][row] = b.x; Bs[col + 1][row] = b.y;
            Bs[col + 2][row] = b.z; Bs[col + 3][row] = b.w;
        }
        __syncthreads();
        #pragma unroll
        for (int kk = 0; kk < BK; ++kk) {
            float a[8], b[8];
            *(float4*)&a[0] = *(const float4*)&As[kk][tm];
            *(float4*)&a[4] = *(const float4*)&As[kk][tm + 4];
            *(float4*)&b[0] = *(const float4*)&Bs[kk][tn];
            *(float4*)&b[4] = *(const float4*)&Bs[kk][tn + 4];
            #pragma unroll
            for (int i = 0; i < 8; ++i)
                #pragma unroll
                for (int j = 0; j < 8; ++j)
                    acc[i][j] = fmaf(a[i], b[j], acc[i][j]);
        }
        __syncthreads();
    }

    #pragma unroll
    for (int i = 0; i < 8; ++i) {
        int m  = bm * BM + tm + i;
        int b_ = m / SEQ, n_ = m % SEQ;
        #pragma unroll
        for (int j = 0; j < 8; ++j) {
            int f   = bn * BN + tn + j;
            int h   = f / 192;
            int rem = f - h * 192;
            int d   = rem / 3;
            int w   = rem - d * 3;
            int bh  = b_ * HEADS + h;
            float v = acc[i][j];
            u16 hi = f2bf(v);
            if (w == 2) {
                Vt[((size_t)bh * HDIM + d) * SEQ + n_] = hi;
            } else {
                u16 lo = f2bf(v - bf2f(hi));
                size_t idx = ((size_t)bh * SEQ + n_) * HDIM + d;
                if (w == 0) { Qhi[idx] = hi; Qlo[idx] = lo; }
                else        { Khi[idx] = hi; Klo[idx] = lo; }
            }
        }
    }
}

// ---------------------------------------------------------------------------
// Proj GEMM (fp32 vector) + bias + relu
// ---------------------------------------------------------------------------
__global__ __launch_bounds__(256)
void proj_gemm(const float* __restrict__ A, const float* __restrict__ W,
               const float* __restrict__ bias, float* __restrict__ Out)
{
    constexpr int BM = 128, BN = 128, BK = 16;
    __shared__ float As[BK][BM + 4];
    __shared__ float Bs[BK][BN + 4];
    const int nbm = MTOT / BM;
    const int bm  = blockIdx.x % nbm;
    const int bn  = blockIdx.x / nbm;
    const int tid = threadIdx.x;
    const int tm  = (tid / 16) * 8;
    const int tn  = (tid % 16) * 8;

    float acc[8][8] = {};
    const float* Ap = A + (size_t)bm * BM * EMBED;
    const float* Wp = W + (size_t)bn * BN * EMBED;

    for (int k0 = 0; k0 < EMBED; k0 += BK) {
        #pragma unroll
        for (int t = 0; t < 2; ++t) {
            int f4  = tid + t * 256;
            int row = f4 >> 2;
            int col = (f4 & 3) * 4;
            float4 a = *reinterpret_cast<const float4*>(&Ap[(size_t)row * EMBED + k0 + col]);
            As[col + 0][row] = a.x; As[col + 1][row] = a.y;
            As[col + 2][row] = a.z; As[col + 3][row] = a.w;
            float4 b = *reinterpret_cast<const float4*>(&Wp[(size_t)row * EMBED + k0 + col]);
            Bs[col + 0][row] = b.x; Bs[col + 1][row] = b.y;
            Bs[col + 2][row] = b.z; Bs[col + 3][row] = b.w;
        }
        __syncthreads();
        #pragma unroll
        for (int kk = 0; kk < BK; ++kk) {
            float a[8], b[8];
            *(float4*)&a[0] = *(const float4*)&As[kk][tm];
            *(float4*)&a[4] = *(const float4*)&As[kk][tm + 4];
            *(float4*)&b[0] = *(const float4*)&Bs[kk][tn];
            *(float4*)&b[4] = *(const float4*)&Bs[kk][tn + 4];
            #pragma unroll
            for (int i = 0; i < 8; ++i)
                #pragma unroll
                for (int j = 0; j < 8; ++j)
                    acc[i][j] = fmaf(a[i], b[j], acc[i][j]);
        }
        __syncthreads();
    }

    #pragma unroll
    for (int i = 0; i < 8; ++i) {
        int m = bm * BM + tm + i;
        #pragma unroll
        for (int j = 0; j < 8; j += 4) {
            int f = bn * BN + tn + j;
            float4 o;
            o.x = fmaxf(acc[i][j + 0] + bias[f + 0], 0.f);
            o.y = fmaxf(acc[i][j + 1] + bias[f + 1], 0.f);
            o.z = fmaxf(acc[i][j + 2] + bias[f + 2], 0.f);
            o.w = fmaxf(acc[i][j + 3] + bias[f + 3], 0.f);
            *(float4*)&Out[(size_t)m * EMBED + f] = o;
        }
    }
}

// ---------------------------------------------------------------------------
// Flash attention via MFMA 32x32x16 bf16.
//  - S^T = K·Q^T with 3-term hi/lo split (QK^T needs ~fp32 score accuracy).
//  - Swapped operands => softmax is lane-local per q-column.
//  - P transposed through per-wave LDS tile, read back as contiguous-k frags.
//  - PV: out^T = V^T·P^T, V pre-transposed in global [bh][d][n].
//  - 4 independent waves/block (32 q rows each), no __syncthreads.
// Fragment layouts (gfx950, 32x32x16): A/B lane l: row/col = l&31,
//   k = (l>>5)*8 + j (8 contiguous). C/D lane l: col = l&31,
//   row = (r&3) + 8*(r>>2) + 4*(l>>5).
// ---------------------------------------------------------------------------
__global__ __launch_bounds__(256)
void attn_mfma(const u16* __restrict__ Qhi, const u16* __restrict__ Qlo,
               const u16* __restrict__ Khi, const u16* __restrict__ Klo,
               const u16* __restrict__ Vt,  float* __restrict__ CTX)
{
    __shared__ __align__(16) u16   Pl[4][32][40];   // per-wave P tile [q][k]
    __shared__ __align__(16) float Ol[4][32][68];   // per-wave out  [q][d]

    const int bid  = blockIdx.x;                    // 512 blocks
    const int swz  = (bid & 7) * 64 + (bid >> 3);   // bijective: 4 heads/XCD
    const int bh   = swz >> 4;                      // 0..31
    const int qt   = swz & 15;                      // 0..15
    const int wid  = threadIdx.x >> 6;
    const int lane = threadIdx.x & 63;
    const int col  = lane & 31;
    const int g    = lane >> 5;

    const int q0 = qt * 128 + wid * 32;
    const int b_ = bh / HEADS;
    const int h  = bh % HEADS;

    // Q fragments (B-operand of S^T): Q[q0+col][16*dt + 8*g + j]
    bf16x8 qh[4], ql[4];
    {
        const u16* qrh = Qhi + ((size_t)bh * SEQ + q0 + col) * HDIM + 8 * g;
        const u16* qrl = Qlo + ((size_t)bh * SEQ + q0 + col) * HDIM + 8 * g;
        #pragma unroll
        for (int dt = 0; dt < 4; ++dt) {
            qh[dt] = *(const bf16x8*)(qrh + 16 * dt);
            ql[dt] = *(const bf16x8*)(qrl + 16 * dt);
        }
    }

    const u16* kbh = Khi + (size_t)bh * SEQ * HDIM + 8 * g;
    const u16* kbl = Klo + (size_t)bh * SEQ * HDIM + 8 * g;
    const u16* vb  = Vt  + (size_t)bh * HDIM * SEQ + 8 * g;

    f32x16 ot0 = {}, ot1 = {};
    float m_run = -3.0e38f, l_run = 0.0f;

    // preload K frags for k0 = 0: K[k0+col][16*dt + 8*g + j]
    bf16x8 kh[4], kl[4];
    #pragma unroll
    for (int dt = 0; dt < 4; ++dt) {
        kh[dt] = *(const bf16x8*)(kbh + (size_t)col * HDIM + 16 * dt);
        kl[dt] = *(const bf16x8*)(kbl + (size_t)col * HDIM + 16 * dt);
    }

    for (int k0 = 0; k0 < SEQ; k0 += 32) {
        // V frags for this iter (A-operand of PV): V^T[dt*32+col][k0+16*kt+8g+j]
        bf16x8 vf[2][2];
        #pragma unroll
        for (int dt = 0; dt < 2; ++dt)
            #pragma unroll
            for (int kt = 0; kt < 2; ++kt)
                vf[dt][kt] = *(const bf16x8*)(vb + (size_t)(dt * 32 + col) * SEQ + k0 + 16 * kt);

        // prefetch next-iter K frags
        bf16x8 nkh[4], nkl[4];
        const bool more = (k0 + 32) < SEQ;
        if (more) {
            #pragma unroll
            for (int dt = 0; dt < 4; ++dt) {
                nkh[dt] = *(const bf16x8*)(kbh + (size_t)(k0 + 32 + col) * HDIM + 16 * dt);
                nkl[dt] = *(const bf16x8*)(kbl + (size_t)(k0 + 32 + col) * HDIM + 16 * dt);
            }
        }

        // S^T = K · Q^T  (hi*hi + hi*lo + lo*hi)
        f32x16 st = {};
        #pragma unroll
        for (int dt = 0; dt < 4; ++dt) {
            st = __builtin_amdgcn_mfma_f32_32x32x16_bf16(kh[dt], qh[dt], st, 0, 0, 0);
            st = __builtin_amdgcn_mfma_f32_32x32x16_bf16(kh[dt], ql[dt], st, 0, 0, 0);
            st = __builtin_amdgcn_mfma_f32_32x32x16_bf16(kl[dt], qh[dt], st, 0, 0, 0);
        }

        // ---- online softmax (per q = col; partner lane is l^32) ----
        float mx = st[0];
        #pragma unroll
        for (int r = 1; r < 16; ++r) mx = fmaxf(mx, st[r]);
        mx = fmaxf(mx, __shfl_xor(mx, 32));
        float m_new = fmaxf(m_run, mx);
        float corr  = __expf(m_run - m_new);

        float psum = 0.0f;
        #pragma unroll
        for (int i = 0; i < 8; ++i) {
            float p0 = __expf(st[2 * i]     - m_new);   // k = ko
            float p1 = __expf(st[2 * i + 1] - m_new);   // k = ko + 1
            psum += p0 + p1;
            int ko = (i & 1) * 2 + (i >> 1) * 8 + 4 * g;
            unsigned w = (unsigned)f2bf(p0) | ((unsigned)f2bf(p1) << 16);
            *(unsigned*)&Pl[wid][col][ko] = w;
        }
        psum += __shfl_xor(psum, 32);
        l_run = l_run * corr + psum;
        ot0 = ot0 * corr;
        ot1 = ot1 * corr;
        m_run = m_new;

        // ---- PV: out^T += V^T · P^T ----
        #pragma unroll
        for (int kt = 0; kt < 2; ++kt) {
            bf16x8 pf = *(const bf16x8*)&Pl[wid][col][16 * kt + 8 * g];
            ot0 = __builtin_amdgcn_mfma_f32_32x32x16_bf16(vf[0][kt], pf, ot0, 0, 0, 0);
            ot1 = __builtin_amdgcn_mfma_f32_32x32x16_bf16(vf[1][kt], pf, ot1, 0, 0, 0);
        }

        if (more) {
            #pragma unroll
            for (int dt = 0; dt < 4; ++dt) { kh[dt] = nkh[dt]; kl[dt] = nkl[dt]; }
        }
    }

    // ---- epilogue: normalize (softmax / 32), transpose via LDS, store ----
    float scale = 1.0f / (l_run * 32.0f);
    #pragma unroll
    for (int r = 0; r < 16; ++r) {
        int d = (r & 3) + 8 * (r >> 2) + 4 * g;
        Ol[wid][col][d]      = ot0[r] * scale;
        Ol[wid][col][d + 32] = ot1[r] * scale;
    }
    #pragma unroll
    for (int pass = 0; pass < 8; ++pass) {
        int qq = pass * 4 + (lane >> 4);
        int dd = (lane & 15) * 4;
        float4 t = *(const float4*)&Ol[wid][qq][dd];
        *(float4*)&CTX[(size_t)(b_ * SEQ + q0 + qq) * EMBED + h * HDIM + dd] = t;
    }
}

extern "C" void kernel_launch(void* const* d_in, const int* in_sizes, int n_in,
                              void* d_out, int out_size, void* d_ws, size_t ws_size,
                              hipStream_t stream)
{
    const float* x      = (const float*)d_in[0];
    const float* w_qkv  = (const float*)d_in[1];
    const float* w_proj = (const float*)d_in[2];
    const float* b_proj = (const float*)d_in[3];
    float* out = (float*)d_out;

    const size_t seg = (size_t)BATCH * HEADS * SEQ * HDIM;   // 4 Mi elems
    char* w = (char*)d_ws;
    u16* Qhi = (u16*)w;               w += seg * 2;
    u16* Qlo = (u16*)w;               w += seg * 2;
    u16* Khi = (u16*)w;               w += seg * 2;
    u16* Klo = (u16*)w;               w += seg * 2;
    u16* Vt  = (u16*)w;               w += seg * 2;
    float* CTX = (float*)w;           // 16 MiB

    qkv_gemm<<<dim3((MTOT / 128) * (3 * EMBED / 128)), 256, 0, stream>>>(
        x, w_qkv, Qhi, Qlo, Khi, Klo, Vt);
    attn_mfma<<<dim3(512), 256, 0, stream>>>(Qhi, Qlo, Khi, Klo, Vt, CTX);
    proj_gemm<<<dim3((MTOT / 128) * (EMBED / 128)), 256, 0, stream>>>(
        CTX, w_proj, b_proj, out);
}

// Round 3
// 357.434 us; speedup vs baseline: 6.9097x; 1.7074x over previous
//
#include <hip/hip_runtime.h>
#include <math.h>

constexpr int EMBED = 1024;
constexpr int HEADS = 16;
constexpr int HDIM  = 64;
constexpr int BATCH = 2;
constexpr int SEQ   = 2048;
constexpr int MTOT  = BATCH * SEQ;   // 4096
constexpr int KSPL  = 3 * EMBED;     // 3072: K' for the 3-term split GEMM
constexpr int LDK   = 2 * EMBED;     // 2048: physical [hi|lo] row width

typedef unsigned short u16;
using bf16x8 = __attribute__((ext_vector_type(8))) short;
using f32x4  = __attribute__((ext_vector_type(4))) float;
using f32x16 = __attribute__((ext_vector_type(16))) float;

__device__ __forceinline__ u16 f2bf(float f) {
    unsigned u = __builtin_bit_cast(unsigned, f);
    return (u16)((u + 0x7fffu + ((u >> 16) & 1u)) >> 16);
}
__device__ __forceinline__ float bf2f(u16 h) {
    unsigned u = ((unsigned)h) << 16;
    return __builtin_bit_cast(float, u);
}

#define GLOAD16(gp, lp) __builtin_amdgcn_global_load_lds( \
    (const __attribute__((address_space(1))) unsigned int*)(gp), \
    (__attribute__((address_space(3))) unsigned int*)(lp), 16, 0, 0)

// ---------------------------------------------------------------------------
// Split f32 rows [rows][1024] into bf16 [rows][2048]: hi at [.][k], lo at
// [.][1024+k]. Handles X, w_qkv, w_proj in one launch (row-ranged).
// ---------------------------------------------------------------------------
__global__ __launch_bounds__(256)
void convert_split(const float* __restrict__ X, const float* __restrict__ Wq,
                   const float* __restrict__ Wp,
                   u16* __restrict__ Xs, u16* __restrict__ Wqs, u16* __restrict__ Wps)
{
    int m = blockIdx.x;                 // 0..8191
    int k = threadIdx.x * 4;
    const float* src; u16* dst;
    if (m < 4096)      { src = X  + (size_t)m * EMBED;          dst = Xs  + (size_t)m * LDK; }
    else if (m < 7168) { int lm = m - 4096; src = Wq + (size_t)lm * EMBED; dst = Wqs + (size_t)lm * LDK; }
    else               { int lm = m - 7168; src = Wp + (size_t)lm * EMBED; dst = Wps + (size_t)lm * LDK; }
    float4 v = *(const float4*)(src + k);
    ushort4 hi, lo;
    hi.x = f2bf(v.x); lo.x = f2bf(v.x - bf2f(hi.x));
    hi.y = f2bf(v.y); lo.y = f2bf(v.y - bf2f(hi.y));
    hi.z = f2bf(v.z); lo.z = f2bf(v.z - bf2f(hi.z));
    hi.w = f2bf(v.w); lo.w = f2bf(v.w - bf2f(hi.w));
    *(ushort4*)(dst + k)         = hi;
    *(ushort4*)(dst + EMBED + k) = lo;
}

// ---------------------------------------------------------------------------
// m97-structure bf16 MFMA mainloop, K'=3072 with per-segment source remap:
//   A segs: [hi | lo | hi]  -> ka = k0<2048 ? k0 : k0-2048
//   B segs: [hi | hi | lo]  -> kb = k0<1024 ? k0 : k0-1024
// 128x128 tile, BK=32, 4 waves (2x2), 4x4 16x16x32 frags per wave.
// LDS tiles linear [row][32] bf16 (64B rows) to satisfy global_load_lds.
// ---------------------------------------------------------------------------
__device__ __forceinline__ void mfma_loop(
    const u16* __restrict__ Ab, const u16* __restrict__ Bb,
    u16* As, u16* Bs, f32x4 (&acc)[4][4], int wid, int lane)
{
    const int wr = wid >> 1, wc = wid & 1;
    const int srow   = lane >> 2;           // staging row within 16-row group
    const int schunk = (lane & 3) * 8;      // staging col (elements)
    const int frow   = lane & 15;
    const int kg8    = (lane >> 4) * 8;     // frag k offset (elements)

    for (int k0 = 0; k0 < KSPL; k0 += 32) {
        const int ka = k0 < 2048 ? k0 : k0 - 2048;
        const int kb = k0 < 1024 ? k0 : k0 - 1024;
        #pragma unroll
        for (int i = 0; i < 2; ++i) {
            const int rbase = wid * 32 + i * 16;
            GLOAD16(Ab + (size_t)(rbase + srow) * LDK + ka + schunk, &As[rbase * 32]);
            GLOAD16(Bb + (size_t)(rbase + srow) * LDK + kb + schunk, &Bs[rbase * 32]);
        }
        __syncthreads();
        bf16x8 a[4], b[4];
        #pragma unroll
        for (int mi = 0; mi < 4; ++mi)
            a[mi] = *(const bf16x8*)&As[(wr * 64 + mi * 16 + frow) * 32 + kg8];
        #pragma unroll
        for (int ni = 0; ni < 4; ++ni)
            b[ni] = *(const bf16x8*)&Bs[(wc * 64 + ni * 16 + frow) * 32 + kg8];
        #pragma unroll
        for (int mi = 0; mi < 4; ++mi)
            #pragma unroll
            for (int ni = 0; ni < 4; ++ni)
                acc[mi][ni] = __builtin_amdgcn_mfma_f32_16x16x32_bf16(
                    a[mi], b[ni], acc[mi][ni], 0, 0, 0);
        __syncthreads();
    }
}

// C element (wave wr,wc): m = bm*128 + wr*64 + mi*16 + (lane>>4)*4 + r
//                         f = bn*128 + wc*64 + ni*16 + (lane&15)
__global__ __launch_bounds__(256)
void gemm_qkv_mfma(const u16* __restrict__ Xs, const u16* __restrict__ Wqs,
                   u16* __restrict__ Qhi, u16* __restrict__ Qlo,
                   u16* __restrict__ Khi, u16* __restrict__ Klo,
                   u16* __restrict__ Vt)
{
    __shared__ __align__(16) u16 As[128 * 32];
    __shared__ __align__(16) u16 Bs[128 * 32];
    const int bid = blockIdx.x;                       // 768
    const int swz = (bid & 7) * 96 + (bid >> 3);
    const int bm  = swz & 31;
    const int bn  = swz >> 5;                         // 0..23
    const int wid = threadIdx.x >> 6, lane = threadIdx.x & 63;
    const int wr = wid >> 1, wc = wid & 1;

    f32x4 acc[4][4] = {};
    mfma_loop(Xs + (size_t)bm * 128 * LDK, Wqs + (size_t)bn * 128 * LDK,
              As, Bs, acc, wid, lane);

    const int b_ = bm >= 16;
    const int n0 = bm * 128 - b_ * SEQ + wr * 64 + ((lane >> 4) << 2);
    #pragma unroll
    for (int ni = 0; ni < 4; ++ni) {
        const int f   = bn * 128 + wc * 64 + ni * 16 + (lane & 15);
        const int h   = f / 192;
        const int rem = f - h * 192;
        const int d   = rem / 3;
        const int w   = rem - d * 3;
        const int bh  = b_ * HEADS + h;
        #pragma unroll
        for (int mi = 0; mi < 4; ++mi) {
            const int n_ = n0 + mi * 16;
            #pragma unroll
            for (int r = 0; r < 4; ++r) {
                float val = acc[mi][ni][r];
                u16 hi = f2bf(val);
                if (w == 2) {
                    Vt[((size_t)bh * HDIM + d) * SEQ + n_ + r] = hi;
                } else {
                    u16 lo = f2bf(val - bf2f(hi));
                    size_t idx = ((size_t)bh * SEQ + n_ + r) * HDIM + d;
                    if (w == 0) { Qhi[idx] = hi; Qlo[idx] = lo; }
                    else        { Khi[idx] = hi; Klo[idx] = lo; }
                }
            }
        }
    }
}

__global__ __launch_bounds__(256)
void gemm_proj_mfma(const u16* __restrict__ CTXs, const u16* __restrict__ Wps,
                    const float* __restrict__ bias, float* __restrict__ Out)
{
    __shared__ __align__(16) u16 As[128 * 32];
    __shared__ __align__(16) u16 Bs[128 * 32];
    const int bid = blockIdx.x;                       // 256
    const int swz = (bid & 7) * 32 + (bid >> 3);
    const int bm  = swz & 31;
    const int bn  = swz >> 5;                         // 0..7
    const int wid = threadIdx.x >> 6, lane = threadIdx.x & 63;
    const int wr = wid >> 1, wc = wid & 1;

    f32x4 acc[4][4] = {};
    mfma_loop(CTXs + (size_t)bm * 128 * LDK, Wps + (size_t)bn * 128 * LDK,
              As, Bs, acc, wid, lane);

    const int m0 = bm * 128 + wr * 64 + ((lane >> 4) << 2);
    #pragma unroll
    for (int ni = 0; ni < 4; ++ni) {
        const int f  = bn * 128 + wc * 64 + ni * 16 + (lane & 15);
        const float bv = bias[f];
        #pragma unroll
        for (int mi = 0; mi < 4; ++mi) {
            const int m = m0 + mi * 16;
            #pragma unroll
            for (int r = 0; r < 4; ++r)
                Out[(size_t)(m + r) * EMBED + f] = fmaxf(acc[mi][ni][r] + bv, 0.f);
        }
    }
}

// ---------------------------------------------------------------------------
// Flash attention via MFMA 32x32x16 bf16 (unchanged core from R2).
// Epilogue now writes CTX as bf16 hi/lo split [m][2048] for the proj GEMM.
// ---------------------------------------------------------------------------
__global__ __launch_bounds__(256)
void attn_mfma(const u16* __restrict__ Qhi, const u16* __restrict__ Qlo,
               const u16* __restrict__ Khi, const u16* __restrict__ Klo,
               const u16* __restrict__ Vt,  u16* __restrict__ CTXs)
{
    __shared__ __align__(16) u16   Pl[4][32][40];
    __shared__ __align__(16) float Ol[4][32][68];

    const int bid  = blockIdx.x;                    // 512
    const int swz  = (bid & 7) * 64 + (bid >> 3);
    const int bh   = swz >> 4;
    const int qt   = swz & 15;
    const int wid  = threadIdx.x >> 6;
    const int lane = threadIdx.x & 63;
    const int col  = lane & 31;
    const int g    = lane >> 5;

    const int q0 = qt * 128 + wid * 32;
    const int b_ = bh / HEADS;
    const int h  = bh % HEADS;

    bf16x8 qh[4], ql[4];
    {
        const u16* qrh = Qhi + ((size_t)bh * SEQ + q0 + col) * HDIM + 8 * g;
        const u16* qrl = Qlo + ((size_t)bh * SEQ + q0 + col) * HDIM + 8 * g;
        #pragma unroll
        for (int dt = 0; dt < 4; ++dt) {
            qh[dt] = *(const bf16x8*)(qrh + 16 * dt);
            ql[dt] = *(const bf16x8*)(qrl + 16 * dt);
        }
    }

    const u16* kbh = Khi + (size_t)bh * SEQ * HDIM + 8 * g;
    const u16* kbl = Klo + (size_t)bh * SEQ * HDIM + 8 * g;
    const u16* vb  = Vt  + (size_t)bh * HDIM * SEQ + 8 * g;

    f32x16 ot0 = {}, ot1 = {};
    float m_run = -3.0e38f, l_run = 0.0f;

    bf16x8 kh[4], kl[4];
    #pragma unroll
    for (int dt = 0; dt < 4; ++dt) {
        kh[dt] = *(const bf16x8*)(kbh + (size_t)col * HDIM + 16 * dt);
        kl[dt] = *(const bf16x8*)(kbl + (size_t)col * HDIM + 16 * dt);
    }

    for (int k0 = 0; k0 < SEQ; k0 += 32) {
        bf16x8 vf[2][2];
        #pragma unroll
        for (int dt = 0; dt < 2; ++dt)
            #pragma unroll
            for (int kt = 0; kt < 2; ++kt)
                vf[dt][kt] = *(const bf16x8*)(vb + (size_t)(dt * 32 + col) * SEQ + k0 + 16 * kt);

        bf16x8 nkh[4], nkl[4];
        const bool more = (k0 + 32) < SEQ;
        if (more) {
            #pragma unroll
            for (int dt = 0; dt < 4; ++dt) {
                nkh[dt] = *(const bf16x8*)(kbh + (size_t)(k0 + 32 + col) * HDIM + 16 * dt);
                nkl[dt] = *(const bf16x8*)(kbl + (size_t)(k0 + 32 + col) * HDIM + 16 * dt);
            }
        }

        f32x16 st = {};
        #pragma unroll
        for (int dt = 0; dt < 4; ++dt) {
            st = __builtin_amdgcn_mfma_f32_32x32x16_bf16(kh[dt], qh[dt], st, 0, 0, 0);
            st = __builtin_amdgcn_mfma_f32_32x32x16_bf16(kh[dt], ql[dt], st, 0, 0, 0);
            st = __builtin_amdgcn_mfma_f32_32x32x16_bf16(kl[dt], qh[dt], st, 0, 0, 0);
        }

        float mx = st[0];
        #pragma unroll
        for (int r = 1; r < 16; ++r) mx = fmaxf(mx, st[r]);
        mx = fmaxf(mx, __shfl_xor(mx, 32));
        float m_new = fmaxf(m_run, mx);
        float corr  = __expf(m_run - m_new);

        float psum = 0.0f;
        #pragma unroll
        for (int i = 0; i < 8; ++i) {
            float p0 = __expf(st[2 * i]     - m_new);
            float p1 = __expf(st[2 * i + 1] - m_new);
            psum += p0 + p1;
            int ko = (i & 1) * 2 + (i >> 1) * 8 + 4 * g;
            unsigned w = (unsigned)f2bf(p0) | ((unsigned)f2bf(p1) << 16);
            *(unsigned*)&Pl[wid][col][ko] = w;
        }
        psum += __shfl_xor(psum, 32);
        l_run = l_run * corr + psum;
        ot0 = ot0 * corr;
        ot1 = ot1 * corr;
        m_run = m_new;

        #pragma unroll
        for (int kt = 0; kt < 2; ++kt) {
            bf16x8 pf = *(const bf16x8*)&Pl[wid][col][16 * kt + 8 * g];
            ot0 = __builtin_amdgcn_mfma_f32_32x32x16_bf16(vf[0][kt], pf, ot0, 0, 0, 0);
            ot1 = __builtin_amdgcn_mfma_f32_32x32x16_bf16(vf[1][kt], pf, ot1, 0, 0, 0);
        }

        if (more) {
            #pragma unroll
            for (int dt = 0; dt < 4; ++dt) { kh[dt] = nkh[dt]; kl[dt] = nkl[dt]; }
        }
    }

    float scale = 1.0f / (l_run * 32.0f);
    #pragma unroll
    for (int r = 0; r < 16; ++r) {
        int d = (r & 3) + 8 * (r >> 2) + 4 * g;
        Ol[wid][col][d]      = ot0[r] * scale;
        Ol[wid][col][d + 32] = ot1[r] * scale;
    }
    #pragma unroll
    for (int pass = 0; pass < 8; ++pass) {
        int qq = pass * 4 + (lane >> 4);
        int dd = (lane & 15) * 4;
        float4 t = *(const float4*)&Ol[wid][qq][dd];
        int m = b_ * SEQ + q0 + qq;
        ushort4 hv, lv;
        hv.x = f2bf(t.x); lv.x = f2bf(t.x - bf2f(hv.x));
        hv.y = f2bf(t.y); lv.y = f2bf(t.y - bf2f(hv.y));
        hv.z = f2bf(t.z); lv.z = f2bf(t.z - bf2f(hv.z));
        hv.w = f2bf(t.w); lv.w = f2bf(t.w - bf2f(hv.w));
        *(ushort4*)&CTXs[(size_t)m * LDK + h * HDIM + dd]         = hv;
        *(ushort4*)&CTXs[(size_t)m * LDK + EMBED + h * HDIM + dd] = lv;
    }
}

extern "C" void kernel_launch(void* const* d_in, const int* in_sizes, int n_in,
                              void* d_out, int out_size, void* d_ws, size_t ws_size,
                              hipStream_t stream)
{
    const float* x      = (const float*)d_in[0];
    const float* w_qkv  = (const float*)d_in[1];
    const float* w_proj = (const float*)d_in[2];
    const float* b_proj = (const float*)d_in[3];
    float* out = (float*)d_out;

    const size_t seg = (size_t)BATCH * HEADS * SEQ * HDIM;   // 4 Mi elems
    char* w = (char*)d_ws;
    u16* Xs   = (u16*)w;  w += (size_t)MTOT * LDK * 2;       // 16 MiB
    u16* Wqs  = (u16*)w;  w += (size_t)3 * EMBED * LDK * 2;  // 12 MiB
    u16* Wps  = (u16*)w;  w += (size_t)EMBED * LDK * 2;      // 4 MiB
    u16* Qhi  = (u16*)w;  w += seg * 2;
    u16* Qlo  = (u16*)w;  w += seg * 2;
    u16* Khi  = (u16*)w;  w += seg * 2;
    u16* Klo  = (u16*)w;  w += seg * 2;
    u16* Vt   = (u16*)w;  w += seg * 2;
    u16* CTXs = Xs;   // Xs is dead after gemm_qkv_mfma; alias (72 MiB total)

    convert_split<<<dim3(8192), 256, 0, stream>>>(x, w_qkv, w_proj, Xs, Wqs, Wps);
    gemm_qkv_mfma<<<dim3(768), 256, 0, stream>>>(Xs, Wqs, Qhi, Qlo, Khi, Klo, Vt);
    attn_mfma<<<dim3(512), 256, 0, stream>>>(Qhi, Qlo, Khi, Klo, Vt, CTXs);
    gemm_proj_mfma<<<dim3(256), 256, 0, stream>>>(CTXs, Wps, b_proj, out);
}